// Round 10
// baseline (1240.393 us; speedup 1.0000x reference)
//
#include <hip/hip_runtime.h>

// Problem constants (B=2, L=2048, D=4096, H=32, HKV=8, HD=128)
#define BB 2
#define LL 2048
#define DD 4096
#define HH 32
#define NKV 8
#define HDIM 128
#define MROWS (BB*LL)   // 4096

typedef __attribute__((ext_vector_type(8))) short bf16x8;     // MFMA A/B operand
typedef __attribute__((ext_vector_type(8))) unsigned short u16x8;
typedef __attribute__((ext_vector_type(4))) unsigned short u16x4;
typedef __attribute__((ext_vector_type(4))) float f32x4;       // MFMA C/D

#define MFMA16(a, b, c) __builtin_amdgcn_mfma_f32_16x16x32_bf16(a, b, c, 0, 0, 0)

__device__ __forceinline__ unsigned short f2bf(float x) {      // RNE f32->bf16
  union { float f; unsigned u; } v; v.f = x;
  unsigned r = v.u + 0x7FFF + ((v.u >> 16) & 1);
  return (unsigned short)(r >> 16);
}
__device__ __forceinline__ float bf2f(unsigned short h) {
  union { unsigned u; float f; } v; v.u = ((unsigned)h) << 16; return v.f;
}
__device__ __forceinline__ unsigned packbf2(float lo, float hi) {
  return ((unsigned)f2bf(hi) << 16) | (unsigned)f2bf(lo);
}
__device__ __forceinline__ void gload_lds16(const void* g, void* l) {
  __builtin_amdgcn_global_load_lds(
      (const __attribute__((address_space(1))) unsigned int*)g,
      (__attribute__((address_space(3))) unsigned int*)l, 16, 0, 0);
}

// ---------------------------------------------------------------------------
// cast fp32 -> bf16 (x must be bf16 for global_load_lds GEMM staging)
// ---------------------------------------------------------------------------
__global__ __launch_bounds__(256) void cast_f32_bf16(
    const float* __restrict__ in, unsigned short* __restrict__ out, int n) {
  int stride = gridDim.x * blockDim.x * 4;
  for (int i = (blockIdx.x * blockDim.x + threadIdx.x) * 4; i < n; i += stride) {
    float4 v = *(const float4*)&in[i];
    u16x4 u;
    u[0] = f2bf(v.x); u[1] = f2bf(v.y); u[2] = f2bf(v.z); u[3] = f2bf(v.w);
    *(u16x4*)&out[i] = u;
  }
}

// ---------------------------------------------------------------------------
// bf16 MFMA NT GEMM: C[M,N] = A[M,K](bf16) * B[N,K](f32->bf16)^T
// 128x128 tile, BK=64, 4 waves (2x2), 4x4 MFMA frags per wave. (unchanged)
// ---------------------------------------------------------------------------
template <bool OUTBF>
__global__ __launch_bounds__(256) void gemm_bt(
    const unsigned short* __restrict__ A, const float* __restrict__ B,
    void* __restrict__ Cv, int M, int N, int K) {
  __shared__ unsigned short As[128 * 64];  // [row][64 k] 128B rows, swizzled
  __shared__ unsigned short Bs[128 * 64];
  const int tid = threadIdx.x;
  const int lane = tid & 63, w = tid >> 6;
  const int l15 = lane & 15, lg = lane >> 4;
  const int wr = w >> 1, wc = w & 1;
  const int brow = blockIdx.y * 128, bcol = blockIdx.x * 128;

  f32x4 acc[4][4];
#pragma unroll
  for (int m = 0; m < 4; ++m)
#pragma unroll
    for (int n = 0; n < 4; ++n)
#pragma unroll
      for (int j = 0; j < 4; ++j) acc[m][n][j] = 0.f;

  for (int k0 = 0; k0 < K; k0 += 64) {
    // A tile: 128x64 bf16 = 1024 x 16B slots, linear dest, swizzled source.
#pragma unroll
    for (int i = 0; i < 4; ++i) {
      int idx = i * 256 + tid;
      int row = idx >> 3, s = idx & 7;
      gload_lds16(&A[(size_t)(brow + row) * K + k0 + ((s ^ (row & 7)) * 8)],
                  &As[idx * 8]);
    }
    // B tile: reg-stage fp32 -> bf16, write phys slot s holding logical col.
#pragma unroll
    for (int i = 0; i < 4; ++i) {
      int f = i * 256 + tid;
      int row = f >> 3, s = f & 7;
      const float* src = &B[(size_t)(bcol + row) * K + k0 + ((s ^ (row & 7)) * 8)];
      float4 f0 = *(const float4*)src;
      float4 f1 = *(const float4*)(src + 4);
      u16x8 u;
      u[0] = f2bf(f0.x); u[1] = f2bf(f0.y); u[2] = f2bf(f0.z); u[3] = f2bf(f0.w);
      u[4] = f2bf(f1.x); u[5] = f2bf(f1.y); u[6] = f2bf(f1.z); u[7] = f2bf(f1.w);
      *(u16x8*)&Bs[f * 8] = u;
    }
    __syncthreads();
#pragma unroll
    for (int kk = 0; kk < 2; ++kk) {
      bf16x8 af[4], bfr[4];
      const int phys = (kk * 4 + lg) ^ (l15 & 7);
#pragma unroll
      for (int m = 0; m < 4; ++m) {
        int row = wr * 64 + m * 16 + l15;
        af[m] = *(const bf16x8*)&As[row * 64 + phys * 8];
      }
#pragma unroll
      for (int n = 0; n < 4; ++n) {
        int row = wc * 64 + n * 16 + l15;
        bfr[n] = *(const bf16x8*)&Bs[row * 64 + phys * 8];
      }
#pragma unroll
      for (int m = 0; m < 4; ++m)
#pragma unroll
        for (int n = 0; n < 4; ++n)
          acc[m][n] = MFMA16(af[m], bfr[n], acc[m][n]);
    }
    __syncthreads();
  }

#pragma unroll
  for (int m = 0; m < 4; ++m)
#pragma unroll
    for (int n = 0; n < 4; ++n)
#pragma unroll
      for (int j = 0; j < 4; ++j) {
        int r = brow + wr * 64 + m * 16 + lg * 4 + j;
        int c = bcol + wc * 64 + n * 16 + l15;
        if (OUTBF)
          ((unsigned short*)Cv)[(size_t)r * N + c] = f2bf(acc[m][n][j]);
        else
          ((float*)Cv)[(size_t)r * N + c] = acc[m][n][j];
      }
}

// ---------------------------------------------------------------------------
// RoPE in place on bf16 q [4096, 4096] and k [4096, 1024]; one u32 = one pair.
// ---------------------------------------------------------------------------
__global__ __launch_bounds__(256) void rope_bf16(
    unsigned* __restrict__ q, unsigned* __restrict__ k,
    const float* __restrict__ cosp, const float* __restrict__ sinp) {
  const int NQ = MROWS * (DD / 2);           // 8.39M q pairs
  const int NT = NQ + MROWS * (NKV * HDIM / 2);
  int stride = gridDim.x * blockDim.x;
  for (int p = blockIdx.x * blockDim.x + threadIdx.x; p < NT; p += stride) {
    bool isq = p < NQ;
    int pp = isq ? p : p - NQ;
    int row = isq ? (pp >> 11) : (pp >> 9);
    int hp  = isq ? (pp & 2047) : (pp & 511);
    int i = hp & 63, l = row & (LL - 1);
    float c = cosp[l * 64 + i], s = sinp[l * 64 + i];
    unsigned* ptr = isq ? (q + (size_t)row * 2048 + hp)
                        : (k + (size_t)row * 512 + hp);
    unsigned v = *ptr;
    float tr = bf2f((unsigned short)(v & 0xffff));
    float ti = bf2f((unsigned short)(v >> 16));
    *ptr = packbf2(tr * c - ti * s, tr * s + ti * c);
  }
}

// ---------------------------------------------------------------------------
// Flash causal GQA attention, bf16 MFMA. 2-phase double-buffered +
// 8 WAVES / 128 Q-ROWS per block (512 thr): 2 blocks/CU -> 16 waves/CU of
// latency-hiding, and KV staging traffic + barriers per key are HALVED.
// Wave w owns q rows [16w,16w+16); KV tile = 64 keys; mask is arithmetic
// (krel0 + kidx > qrel), active only for the last two tiles of each wave.
// ---------------------------------------------------------------------------
__global__ __launch_bounds__(512) void attn_mfma(
    const unsigned short* __restrict__ Qb, const unsigned short* __restrict__ Kb,
    const unsigned short* __restrict__ Vb, unsigned short* __restrict__ Ob) {
  __shared__ unsigned short Ks[2][64 * 128];  // [key][dim] 16-slot swz, 16KB ea
  __shared__ unsigned short Vt[2][128 * 64];  // [dim][key]  8-slot swz, 16KB ea
  const int tid = threadIdx.x;
  const int lane = tid & 63, w = tid >> 6;     // w in 0..7
  const int l15 = lane & 15, lg = lane >> 4;
  const int qb = (int)gridDim.x - 1 - (int)blockIdx.x;  // heavy blocks first
  const int bh = blockIdx.y;
  const int b = bh >> 5, h = bh & 31, kvh = h >> 2;
  const int qrel = w * 16 + l15;               // 0..127
  const size_t qrow = (size_t)(b * LL + qb * 128 + qrel);

  bf16x8 qf[4];
#pragma unroll
  for (int c = 0; c < 4; ++c)
    qf[c] = *(const bf16x8*)&Qb[qrow * DD + h * HDIM + c * 32 + lg * 8];

  f32x4 oacc[8];
#pragma unroll
  for (int d = 0; d < 8; ++d)
#pragma unroll
    for (int j = 0; j < 4; ++j) oacc[d][j] = 0.f;
  float mrun = -1e30f, lrun = 0.f;
  const float scale = 0.08838834764831845f;  // 1/sqrt(128)
  const int kmaxt = 2 * (qb + 1);            // 64-key tiles needed

  // --- staging helpers (512 threads: 2 iterations each) --------------------
  auto stageK = [&](int nb, int t) {  // K tile via global_load_lds, linear dest
#pragma unroll
    for (int i = 0; i < 2; ++i) {
      int idx = i * 512 + tid;
      int krow = idx >> 4, slot = idx & 15;
      gload_lds16(&Kb[(size_t)(b * LL + t * 64 + krow) * (NKV * HDIM) +
                      kvh * HDIM + ((slot ^ (krow & 15)) * 8)],
                  &Ks[nb][idx * 8]);
    }
  };
  auto loadV = [&](int t, u16x8* vreg) {  // V tile global -> regs (issue-early)
#pragma unroll
    for (int i = 0; i < 2; ++i) {
      int f = i * 512 + tid;
      int key = f & 63, d0 = (f >> 6) * 8;
      vreg[i] = *(const u16x8*)&Vb[(size_t)(b * LL + t * 64 + key) *
                                   (NKV * HDIM) + kvh * HDIM + d0];
    }
  };
  auto writeV = [&](int nb, const u16x8* vreg) {  // regs -> transposed LDS
#pragma unroll
    for (int i = 0; i < 2; ++i) {
      int f = i * 512 + tid;
      int key = f & 63, d0 = (f >> 6) * 8;
#pragma unroll
      for (int j = 0; j < 8; ++j) {
        int dim = d0 + j;
        Vt[nb][dim * 64 + (((key >> 3) ^ (dim & 7)) * 8) + (key & 7)] = vreg[i][j];
      }
    }
  };

  // --- per-tile compute ----------------------------------------------------
  auto compute = [&](int nb, int t0) {
    // S^T[64key][16q] = K * Q^T
    f32x4 sa[4];
    __builtin_amdgcn_s_setprio(1);
#pragma unroll
    for (int mb = 0; mb < 4; ++mb) {
#pragma unroll
      for (int j = 0; j < 4; ++j) sa[mb][j] = 0.f;
#pragma unroll
      for (int c = 0; c < 4; ++c) {
        int row = mb * 16 + l15;
        int phys = (c * 4 + lg) ^ l15;  // 16-slot swizzle
        bf16x8 kf = *(const bf16x8*)&Ks[nb][row * 128 + phys * 8];
        sa[mb] = MFMA16(kf, qf[c], sa[mb]);
      }
    }
    __builtin_amdgcn_s_setprio(0);

    // scale + causal mask (arithmetic; hot only on each wave's last 2 tiles)
    const int krel0 = t0 * 64 - qb * 128;    // key offset rel. to q base
    const bool boundary = (krel0 + 63 > w * 16);
#pragma unroll
    for (int mb = 0; mb < 4; ++mb)
#pragma unroll
      for (int j = 0; j < 4; ++j) {
        float s = sa[mb][j] * scale;
        if (boundary && (krel0 + mb * 16 + lg * 4 + j > qrel)) s = -1e30f;
        sa[mb][j] = s;
      }
    float vm = -1e30f;
#pragma unroll
    for (int mb = 0; mb < 4; ++mb)
#pragma unroll
      for (int j = 0; j < 4; ++j) vm = fmaxf(vm, sa[mb][j]);
    vm = fmaxf(vm, __shfl_xor(vm, 16));
    vm = fmaxf(vm, __shfl_xor(vm, 32));
    float mnew = fmaxf(mrun, vm);
    float corr = __expf(mrun - mnew);
    float psum = 0.f;
#pragma unroll
    for (int mb = 0; mb < 4; ++mb)
#pragma unroll
      for (int j = 0; j < 4; ++j) {
        float p = __expf(sa[mb][j] - mnew);
        sa[mb][j] = p;
        psum += p;
      }
    psum += __shfl_xor(psum, 16);
    psum += __shfl_xor(psum, 32);
    lrun = lrun * corr + psum;
    mrun = mnew;
#pragma unroll
    for (int d = 0; d < 8; ++d)
#pragma unroll
      for (int j = 0; j < 4; ++j) oacc[d][j] *= corr;

    // pack P to bf16 pairs: pk[mb][0]=(j0,j1), pk[mb][1]=(j2,j3)
    unsigned pk[4][2];
#pragma unroll
    for (int mb = 0; mb < 4; ++mb) {
      pk[mb][0] = packbf2(sa[mb][0], sa[mb][1]);
      pk[mb][1] = packbf2(sa[mb][2], sa[mb][3]);
    }

    // PV: O^T[128dim][16q] += V^T * P^T  (two K=32 halves)
#pragma unroll
    for (int kh = 0; kh < 2; ++kh) {
      unsigned pbu[4];
#pragma unroll
      for (int r = 0; r < 4; ++r) {
        int srcl = l15 + 16 * ((lg & 1) * 2 + (r >> 1));
        unsigned va = (unsigned)__shfl((int)pk[2 * kh][r & 1], srcl);
        unsigned vb = (unsigned)__shfl((int)pk[2 * kh + 1][r & 1], srcl);
        pbu[r] = (lane & 32) ? vb : va;
      }
      bf16x8 pb;
#pragma unroll
      for (int r = 0; r < 4; ++r) {
        pb[2 * r]     = (short)(pbu[r] & 0xffff);
        pb[2 * r + 1] = (short)(pbu[r] >> 16);
      }
      const int phys = ((kh * 4 + lg) ^ (l15 & 7));
      __builtin_amdgcn_s_setprio(1);
#pragma unroll
      for (int mbd = 0; mbd < 8; ++mbd) {
        int row = mbd * 16 + l15;
        bf16x8 vf = *(const bf16x8*)&Vt[nb][row * 64 + phys * 8];
        oacc[mbd] = MFMA16(vf, pb, oacc[mbd]);
      }
      __builtin_amdgcn_s_setprio(0);
    }
  };

  // --- 2-phase pipeline ----------------------------------------------------
  u16x8 vreg[2];
  stageK(0, 0);                 // prologue: tile 0 -> buf 0
  loadV(0, vreg);
  writeV(0, vreg);              // compiler inserts vmcnt wait for vreg
  __syncthreads();              // drains K gload_lds (vmcnt 0) + ds_writes

  int cur = 0;
  for (int t0 = 0; t0 < kmaxt - 1; ++t0) {
    stageK(cur ^ 1, t0 + 1);    // issue next-tile loads BEFORE compute
    loadV(t0 + 1, vreg);
    compute(cur, t0);           // load latency hides under compute
    writeV(cur ^ 1, vreg);      // write-late (T14)
    __syncthreads();            // single barrier per tile
    cur ^= 1;
  }
  compute(cur, kmaxt - 1);      // last tile (always boundary-masked)

  // epilogue: O^T frag (dim=mbd*16+lg*4+j, q=l15) -> bf16 rows of attn buffer
  float inv = 1.f / lrun;
#pragma unroll
  for (int mbd = 0; mbd < 8; ++mbd)
#pragma unroll
    for (int j = 0; j < 4; j += 2) {
      int dim = mbd * 16 + lg * 4 + j;
      unsigned pk2 = packbf2(oacc[mbd][j] * inv, oacc[mbd][j + 1] * inv);
      *(unsigned*)&Ob[qrow * DD + h * HDIM + dim] = pk2;
    }
}

// ---------------------------------------------------------------------------
// Launch graph: cast(x) ; q,k,v GEMMs ; rope ; attn ; out GEMM
// ws (bytes): xb 32M | qbf 32M | kbf 8M | vbf 8M | attnbf 32M = 112 MB
// ---------------------------------------------------------------------------
extern "C" void kernel_launch(void* const* d_in, const int* in_sizes, int n_in,
                              void* d_out, int out_size, void* d_ws, size_t ws_size,
                              hipStream_t stream) {
  const float* x    = (const float*)d_in[0];
  const float* wq   = (const float*)d_in[1];
  const float* wk   = (const float*)d_in[2];
  const float* wv   = (const float*)d_in[3];
  const float* wo   = (const float*)d_in[4];
  const float* cosp = (const float*)d_in[5];
  const float* sinp = (const float*)d_in[6];
  float* out = (float*)d_out;

  unsigned short* xb     = (unsigned short*)d_ws;
  unsigned short* qbf    = xb + (size_t)MROWS * DD;
  unsigned short* kbf    = qbf + (size_t)MROWS * DD;
  unsigned short* vbf    = kbf + (size_t)MROWS * (NKV * HDIM);
  unsigned short* attnbf = vbf + (size_t)MROWS * (NKV * HDIM);

  dim3 blk(256);
  cast_f32_bf16<<<4096, blk, 0, stream>>>(x, xb, MROWS * DD);
  gemm_bt<true><<<dim3(DD / 128, MROWS / 128), blk, 0, stream>>>(
      xb, wq, qbf, MROWS, DD, DD);
  gemm_bt<true><<<dim3((NKV * HDIM) / 128, MROWS / 128), blk, 0, stream>>>(
      xb, wk, kbf, MROWS, NKV * HDIM, DD);
  gemm_bt<true><<<dim3((NKV * HDIM) / 128, MROWS / 128), blk, 0, stream>>>(
      xb, wv, vbf, MROWS, NKV * HDIM, DD);
  rope_bf16<<<8192, blk, 0, stream>>>((unsigned*)qbf, (unsigned*)kbf, cosp, sinp);
  attn_mfma<<<dim3(LL / 128, BB * HH), dim3(512), 0, stream>>>(qbf, kbf, vbf, attnbf);
  gemm_bt<false><<<dim3(DD / 128, MROWS / 128), blk, 0, stream>>>(
      attnbf, wo, out, MROWS, DD, DD);
}